// Round 1
// baseline (959.113 us; speedup 1.0000x reference)
//
#include <hip/hip_runtime.h>
#include <cstdint>
#include <cstddef>

#define D 128

// ---------------- CSR build ----------------

__global__ __launch_bounds__(256) void hist_kernel(const int* __restrict__ eidx,
                                                   int* __restrict__ counts, int E) {
    int e = blockIdx.x * 256 + threadIdx.x;
    if (e < E) atomicAdd(&counts[eidx[E + e]], 1);
}

__global__ __launch_bounds__(1024) void scan_kernel(const int* __restrict__ counts,
                                                    int* __restrict__ row_start,
                                                    int* __restrict__ cursor,
                                                    int N, int E) {
    __shared__ int lsum[1024];
    int t = threadIdx.x;
    int chunk = (N + 1023) >> 10;
    int lo = t * chunk; if (lo > N) lo = N;
    int hi = lo + chunk; if (hi > N) hi = N;
    int s = 0;
    for (int i = lo; i < hi; ++i) s += counts[i];
    lsum[t] = s;
    __syncthreads();
    // in-place Hillis-Steele inclusive scan
    for (int off = 1; off < 1024; off <<= 1) {
        int v = (t >= off) ? lsum[t - off] : 0;
        __syncthreads();
        lsum[t] += v;
        __syncthreads();
    }
    int run = lsum[t] - s;   // exclusive prefix at chunk start
    for (int i = lo; i < hi; ++i) {
        row_start[i] = run;
        cursor[i] = run;
        run += counts[i];
    }
    if (t == 0) row_start[N] = E;
}

__global__ __launch_bounds__(256) void scatter_ids_kernel(const int* __restrict__ eidx,
                                                          int* __restrict__ cursor,
                                                          int* __restrict__ ebuf, int E) {
    int e = blockIdx.x * 256 + threadIdx.x;
    if (e < E) {
        int dst = eidx[E + e];
        int pos = atomicAdd(&cursor[dst], 1);
        ebuf[pos] = e;
    }
}

// ---------------- gather: h = x + sum_in relu(x[src] + edge_attr) ----------------

__global__ __launch_bounds__(256) void gather_kernel(const int* __restrict__ eidx,
                                                     const float* __restrict__ x,
                                                     const float* __restrict__ ea,
                                                     const int* __restrict__ row_start,
                                                     const int* __restrict__ ebuf,
                                                     float* __restrict__ hbuf, int N) {
    int wave = (blockIdx.x * 256 + threadIdx.x) >> 6;
    int lane = threadIdx.x & 63;
    if (wave >= N) return;
    int s = row_start[wave];
    int e = row_start[wave + 1];
    float a0 = 0.f, a1 = 0.f;
    for (int j = s; j < e; ++j) {
        int eid = ebuf[j];
        int src = eidx[eid];
        float2 eav = *(const float2*)(ea + (size_t)eid * D + lane * 2);
        float2 xsv = *(const float2*)(x + (size_t)src * D + lane * 2);
        float m0 = xsv.x + eav.x; m0 = m0 > 0.f ? m0 : 0.f;
        float m1 = xsv.y + eav.y; m1 = m1 > 0.f ? m1 : 0.f;
        a0 += m0; a1 += m1;
    }
    float2 xv = *(const float2*)(x + (size_t)wave * D + lane * 2);
    float2 hv; hv.x = xv.x + a0; hv.y = xv.y + a1;
    *(float2*)(hbuf + (size_t)wave * D + lane * 2) = hv;
}

// ---------------- fused MLP + residual: out = x + relu(h W1 + b1) W2 + b2 ----------------

__global__ __launch_bounds__(256) void mlp_kernel(const float* __restrict__ hbuf,
                                                  const float* __restrict__ x,
                                                  const float* __restrict__ W1,
                                                  const float* __restrict__ b1,
                                                  const float* __restrict__ W2,
                                                  const float* __restrict__ b2,
                                                  float* __restrict__ out, int N) {
    __shared__ float hs[64][D];
    int tid = threadIdx.x;
    int row0 = blockIdx.x * 64;
    // stage 64x128 h tile (coalesced float4)
#pragma unroll
    for (int i = 0; i < 8; ++i) {
        int idx = i * 256 + tid;        // 2048 float4 slots
        int r = idx >> 5;
        int c = (idx & 31) * 4;
        int row = row0 + r;
        float4 v = make_float4(0.f, 0.f, 0.f, 0.f);
        if (row < N) v = *(const float4*)(hbuf + (size_t)row * D + c);
        *(float4*)&hs[r][c] = v;
    }
    __syncthreads();

    int cg = (tid & 31) * 4;   // 4 output cols
    int rg = (tid >> 5) * 8;   // 8 rows

    float4 acc[8];
    {
        float4 bv = *(const float4*)(b1 + cg);
#pragma unroll
        for (int r = 0; r < 8; ++r) acc[r] = bv;
    }
    for (int k4 = 0; k4 < 32; ++k4) {
        float4 hv[8];
#pragma unroll
        for (int r = 0; r < 8; ++r) hv[r] = *(const float4*)&hs[rg + r][k4 * 4];
#pragma unroll
        for (int kk = 0; kk < 4; ++kk) {
            float4 w = *(const float4*)(W1 + (size_t)(k4 * 4 + kk) * D + cg);
#pragma unroll
            for (int r = 0; r < 8; ++r) {
                float h = ((const float*)&hv[r])[kk];
                acc[r].x += h * w.x; acc[r].y += h * w.y;
                acc[r].z += h * w.z; acc[r].w += h * w.w;
            }
        }
    }
    __syncthreads();   // everyone done reading hs
#pragma unroll
    for (int r = 0; r < 8; ++r) {
        float4 o = acc[r];
        o.x = o.x > 0.f ? o.x : 0.f; o.y = o.y > 0.f ? o.y : 0.f;
        o.z = o.z > 0.f ? o.z : 0.f; o.w = o.w > 0.f ? o.w : 0.f;
        *(float4*)&hs[rg + r][cg] = o;
    }
    __syncthreads();

    {
        float4 bv = *(const float4*)(b2 + cg);
#pragma unroll
        for (int r = 0; r < 8; ++r) acc[r] = bv;
    }
    for (int k4 = 0; k4 < 32; ++k4) {
        float4 hv[8];
#pragma unroll
        for (int r = 0; r < 8; ++r) hv[r] = *(const float4*)&hs[rg + r][k4 * 4];
#pragma unroll
        for (int kk = 0; kk < 4; ++kk) {
            float4 w = *(const float4*)(W2 + (size_t)(k4 * 4 + kk) * D + cg);
#pragma unroll
            for (int r = 0; r < 8; ++r) {
                float h = ((const float*)&hv[r])[kk];
                acc[r].x += h * w.x; acc[r].y += h * w.y;
                acc[r].z += h * w.z; acc[r].w += h * w.w;
            }
        }
    }
#pragma unroll
    for (int r = 0; r < 8; ++r) {
        int row = row0 + rg + r;
        if (row < N) {
            float4 xv = *(const float4*)(x + (size_t)row * D + cg);
            float4 o;
            o.x = acc[r].x + xv.x; o.y = acc[r].y + xv.y;
            o.z = acc[r].z + xv.z; o.w = acc[r].w + xv.w;
            *(float4*)(out + (size_t)row * D + cg) = o;
        }
    }
}

// ---------------- BatchNorm ----------------

__global__ __launch_bounds__(256) void stats_kernel(const float* __restrict__ out,
                                                    float* __restrict__ stats, int N) {
    int f = threadIdx.x & 127;
    int half = threadIdx.x >> 7;
    int rpb = (N + gridDim.x - 1) / gridDim.x;
    int r0 = blockIdx.x * rpb;
    int r1 = r0 + rpb; if (r1 > N) r1 = N;
    float s = 0.f, ss = 0.f;
    for (int r = r0 + half; r < r1; r += 2) {
        float v = out[(size_t)r * D + f];
        s += v; ss += v * v;
    }
    __shared__ float sh[2][128];
    __shared__ float sq[2][128];
    sh[half][f] = s; sq[half][f] = ss;
    __syncthreads();
    if (half == 0) {
        atomicAdd(&stats[f], sh[0][f] + sh[1][f]);
        atomicAdd(&stats[128 + f], sq[0][f] + sq[1][f]);
    }
}

__global__ __launch_bounds__(128) void bnprep_kernel(float* __restrict__ stats,
                                                     const float* __restrict__ gamma,
                                                     const float* __restrict__ beta,
                                                     float invN) {
    int f = threadIdx.x;
    float mean = stats[f] * invN;
    float var = stats[128 + f] * invN - mean * mean;
    float scale = rsqrtf(var + 1e-5f) * gamma[f];
    float shift = beta[f] - mean * scale;
    stats[f] = scale;
    stats[128 + f] = shift;
}

__global__ __launch_bounds__(256) void norm_kernel(float* __restrict__ out,
                                                   const float* __restrict__ stats,
                                                   int total4) {
    int i = blockIdx.x * 256 + threadIdx.x;
    if (i >= total4) return;
    int c = (i & 31) * 4;
    float4 v = ((const float4*)out)[i];
    float4 sc = *(const float4*)&stats[c];
    float4 sf = *(const float4*)&stats[128 + c];
    v.x = v.x * sc.x + sf.x; v.y = v.y * sc.y + sf.y;
    v.z = v.z * sc.z + sf.z; v.w = v.w * sc.w + sf.w;
    ((float4*)out)[i] = v;
}

// ---------------- launch ----------------

static inline size_t align_up(size_t v, size_t a) { return (v + a - 1) & ~(a - 1); }

extern "C" void kernel_launch(void* const* d_in, const int* in_sizes, int n_in,
                              void* d_out, int out_size, void* d_ws, size_t ws_size,
                              hipStream_t stream) {
    const float* x     = (const float*)d_in[0];
    const int*   eidx  = (const int*)d_in[1];
    const float* ea    = (const float*)d_in[2];
    const float* W1    = (const float*)d_in[3];
    const float* b1    = (const float*)d_in[4];
    const float* W2    = (const float*)d_in[5];
    const float* b2    = (const float*)d_in[6];
    const float* gamma = (const float*)d_in[7];
    const float* beta  = (const float*)d_in[8];
    float* out = (float*)d_out;

    int N = in_sizes[0] / D;
    int E = in_sizes[1] / 2;

    char* ws = (char*)d_ws;
    size_t off = 0;
    float* hbuf = (float*)(ws + off);      off = align_up(off + (size_t)N * D * sizeof(float), 256);
    int* counts = (int*)(ws + off);        off = align_up(off + (size_t)N * sizeof(int), 256);
    int* row_start = (int*)(ws + off);     off = align_up(off + (size_t)(N + 1) * sizeof(int), 256);
    int* cursor = (int*)(ws + off);        off = align_up(off + (size_t)N * sizeof(int), 256);
    int* ebuf = (int*)(ws + off);          off = align_up(off + (size_t)E * sizeof(int), 256);
    float* stats = (float*)(ws + off);     off = align_up(off + 256 * sizeof(float), 256);

    hipMemsetAsync(counts, 0, (size_t)N * sizeof(int), stream);
    hipMemsetAsync(stats, 0, 256 * sizeof(float), stream);

    hist_kernel<<<(E + 255) / 256, 256, 0, stream>>>(eidx, counts, E);
    scan_kernel<<<1, 1024, 0, stream>>>(counts, row_start, cursor, N, E);
    scatter_ids_kernel<<<(E + 255) / 256, 256, 0, stream>>>(eidx, cursor, ebuf, E);
    gather_kernel<<<(N + 3) / 4, 256, 0, stream>>>(eidx, x, ea, row_start, ebuf, hbuf, N);
    mlp_kernel<<<(N + 63) / 64, 256, 0, stream>>>(hbuf, x, W1, b1, W2, b2, out, N);
    stats_kernel<<<256, 256, 0, stream>>>(out, stats, N);
    bnprep_kernel<<<1, 128, 0, stream>>>(stats, gamma, beta, 1.0f / (float)N);
    norm_kernel<<<(N * (D / 4) + 255) / 256, 256, 0, stream>>>(out, stats, N * (D / 4));
}